// Round 3
// baseline (313.329 us; speedup 1.0000x reference)
//
#include <hip/hip_runtime.h>
#include <hip/hip_bf16.h>
#include <stdint.h>

#define M_TOK 8192
#define N_OUT 4096
#define K_IN  4096

#define BM 256
#define BN 256
#define BK 64
#define NT (K_IN / BK)   // 64 K-tiles

typedef __attribute__((ext_vector_type(8)))  __bf16 bf16x8;
typedef __attribute__((ext_vector_type(16))) float  f32x16;

#define AS1 __attribute__((address_space(1)))
#define AS3 __attribute__((address_space(3)))
#define GLOAD_LDS16(g, l) \
  __builtin_amdgcn_global_load_lds((AS1 void*)(g), (AS3 void*)(l), 16, 0, 0)

#define BAR()    __builtin_amdgcn_s_barrier()
#define LGKM0()  do { asm volatile("s_waitcnt lgkmcnt(0)" ::: "memory"); \
                      __builtin_amdgcn_sched_barrier(0); } while (0)
#define VMCNT6() asm volatile("s_waitcnt vmcnt(6)" ::: "memory")
#define VMCNT0() asm volatile("s_waitcnt vmcnt(0)" ::: "memory")
#define PRIO(p)  __builtin_amdgcn_s_setprio(p)
#define MFMA32(a, b, c) __builtin_amdgcn_mfma_f32_32x32x16_bf16((a), (b), (c), 0, 0, 0)

// ---------------- prep: x fp32 -> bf16 (RNE via fptrunc) ----------------
__global__ __launch_bounds__(256) void cvt_x_bf16(const float4* __restrict__ x,
                                                  ushort4* __restrict__ o, int n4) {
  int i = blockIdx.x * blockDim.x + threadIdx.x;
  int stride = gridDim.x * blockDim.x;
  for (; i < n4; i += stride) {
    float4 v = x[i];
    ushort4 r;
    r.x = __builtin_bit_cast(unsigned short, (__bf16)v.x);
    r.y = __builtin_bit_cast(unsigned short, (__bf16)v.y);
    r.z = __builtin_bit_cast(unsigned short, (__bf16)v.z);
    r.w = __builtin_bit_cast(unsigned short, (__bf16)v.w);
    o[i] = r;
  }
}

// ---------------- prep: W fp32 -> sign in bf16 ----------------
__global__ __launch_bounds__(256) void sgn_w_bf16(const float4* __restrict__ w,
                                                  ushort4* __restrict__ o, int n4) {
  int i = blockIdx.x * blockDim.x + threadIdx.x;
  int stride = gridDim.x * blockDim.x;
  for (; i < n4; i += stride) {
    float4 v = w[i];
    ushort4 r;
    r.x = v.x > 0.f ? 0x3F80 : (v.x < 0.f ? 0xBF80 : 0);
    r.y = v.y > 0.f ? 0x3F80 : (v.y < 0.f ? 0xBF80 : 0);
    r.z = v.z > 0.f ? 0x3F80 : (v.z < 0.f ? 0xBF80 : 0);
    r.w = v.w > 0.f ? 0x3F80 : (v.w < 0.f ? 0xBF80 : 0);
    o[i] = r;
  }
}

// ======== 256x256 8-phase GEMM, 32x32x16 MFMA: C = A[M][K] * B[N][K]^T ========
// 8 waves (2Mx4N), per-wave 128x64 out = acc[4][2] f32x16.
// Phases per K-tile (reads/MFMA balanced 8/8/8/0 + 8/8/8/8):
//   p0: read a[0..1][kf0..1]+b[0..1][kf0..1]; stage A1(t+1); MFMA m01 x n01 x kf01
//   p1: read a[0..1][kf2..3]+b[0..1][kf2..3];                MFMA m01 x n01 x kf23
//   p2: read a[2..3][kf0..3];                 stage B0(t+2); MFMA m23 x n01 x kf01
//   p3:                                stage B1(t+2),A0(t+2); MFMA m23 x n01 x kf23
// Region deadness (stage safety): all B reads done by p1-end; all A reads by
// p2-end -> identical staging/vmcnt(6) invariant as round 2 (verified).
__global__ __launch_bounds__(512, 2) void bin_gemm256(const __bf16* __restrict__ A,
                                                      const __bf16* __restrict__ B,
                                                      float* __restrict__ C) {
  __shared__ char lds[131072];   // 2 buf x (A 32KB + B 32KB)

  const int tid  = threadIdx.x;
  const int w    = tid >> 6;
  const int lane = tid & 63;
  const int l5   = lane & 31;    // row/col within 32
  const int hi   = lane >> 5;    // k-half selector (8 bf16 each)
  const int wr   = w >> 2;       // wave row 0..1 (128 rows)
  const int wc   = w & 3;        // wave col 0..3 (64 cols)

  const int bm = blockIdx.x >> 4;     // M/256 = 32
  const int bn = blockIdx.x & 15;     // N/256 = 16

  const char* Ag = (const char*)(A + (size_t)bm * BM * K_IN);
  const char* Bg = (const char*)(B + (size_t)bn * BN * K_IN);

  // staging: linear LDS dest + inverse-swizzled global source (rule #21).
  // chunk c of a 128-row half: row r=c>>3, source slot (c^r)&7 -> LDS[r][s] = G[r][s^(r&7)]
  const int c0 = w * 128 + lane;
  const int c1 = c0 + 64;
  const int r0 = c0 >> 3, r1 = c1 >> 3;
  const size_t g0 = (size_t)r0 * (K_IN * 2) + (size_t)(((c0 ^ r0) & 7) << 4);
  const size_t g1 = (size_t)r1 * (K_IN * 2) + (size_t)(((c1 ^ r1) & 7) << 4);
  const int ldsw = w * 128 * 16;

  auto stage = [&](int mat, int half, int tt) {
    const char* g = (mat ? Bg : Ag) + (size_t)half * (128 * K_IN * 2)
                                    + (size_t)tt * (BK * 2);
    char* l = &lds[((tt & 1) << 16) + (mat << 15) + (half << 14) + ldsw];
    GLOAD_LDS16(g + g0, l);
    GLOAD_LDS16(g + g1, l + 1024);
  };

  // fragment reads (swizzled): region + (rowbase+l5)*128 + ((kf*32+hi*16) ^ ((l5&7)<<4))
  const int swz    = (l5 & 7) << 4;
  const int a_base = (wr * 128 + l5) * 128;
  const int b_base = 32768 + (wc * 64 + l5) * 128;
#define AK(L, m, kf) (*(const bf16x8*)((L) + a_base + (m)*4096 + ((((kf)*32) + hi*16) ^ swz)))
#define BKF(L, n, kf) (*(const bf16x8*)((L) + b_base + (n)*4096 + ((((kf)*32) + hi*16) ^ swz)))

  f32x16 acc[4][2];
  #pragma unroll
  for (int m = 0; m < 4; ++m)
    #pragma unroll
    for (int n = 0; n < 2; ++n)
      #pragma unroll
      for (int r = 0; r < 16; ++r) acc[m][n][r] = 0.f;

  // prologue: tile 0 complete + {B0,B1,A0}(1) in flight (6 loads outstanding)
  stage(0, 0, 0); stage(0, 1, 0); stage(1, 0, 0); stage(1, 1, 0);
  stage(1, 0, 1); stage(1, 1, 1); stage(0, 0, 1);
  VMCNT6();
  BAR();

  for (int t = 0; t < NT; ++t) {
    const char* L = &lds[(size_t)(t & 1) << 16];
    bf16x8 aL[2][2], aH[2][4], bf[2][4];

    // ---------- phase 0: a[0..1][0..1] + b[0..1][0..1] (8 reads); stage A1(t+1)
    aL[0][0] = AK(L, 0, 0); aL[0][1] = AK(L, 0, 1);
    aL[1][0] = AK(L, 1, 0); aL[1][1] = AK(L, 1, 1);
    bf[0][0] = BKF(L, 0, 0); bf[0][1] = BKF(L, 0, 1);
    bf[1][0] = BKF(L, 1, 0); bf[1][1] = BKF(L, 1, 1);
    if (t + 1 < NT) stage(0, 1, t + 1);
    BAR(); LGKM0(); PRIO(1);
    acc[0][0] = MFMA32(aL[0][0], bf[0][0], acc[0][0]);
    acc[0][0] = MFMA32(aL[0][1], bf[0][1], acc[0][0]);
    acc[0][1] = MFMA32(aL[0][0], bf[1][0], acc[0][1]);
    acc[0][1] = MFMA32(aL[0][1], bf[1][1], acc[0][1]);
    acc[1][0] = MFMA32(aL[1][0], bf[0][0], acc[1][0]);
    acc[1][0] = MFMA32(aL[1][1], bf[0][1], acc[1][0]);
    acc[1][1] = MFMA32(aL[1][0], bf[1][0], acc[1][1]);
    acc[1][1] = MFMA32(aL[1][1], bf[1][1], acc[1][1]);
    PRIO(0); BAR();

    // ---------- phase 1: a[0..1][2..3] + b[0..1][2..3] (8 reads)
    aL[0][0] = AK(L, 0, 2); aL[0][1] = AK(L, 0, 3);
    aL[1][0] = AK(L, 1, 2); aL[1][1] = AK(L, 1, 3);
    bf[0][2] = BKF(L, 0, 2); bf[0][3] = BKF(L, 0, 3);
    bf[1][2] = BKF(L, 1, 2); bf[1][3] = BKF(L, 1, 3);
    BAR(); LGKM0(); PRIO(1);
    acc[0][0] = MFMA32(aL[0][0], bf[0][2], acc[0][0]);
    acc[0][0] = MFMA32(aL[0][1], bf[0][3], acc[0][0]);
    acc[0][1] = MFMA32(aL[0][0], bf[1][2], acc[0][1]);
    acc[0][1] = MFMA32(aL[0][1], bf[1][3], acc[0][1]);
    acc[1][0] = MFMA32(aL[1][0], bf[0][2], acc[1][0]);
    acc[1][0] = MFMA32(aL[1][1], bf[0][3], acc[1][0]);
    acc[1][1] = MFMA32(aL[1][0], bf[1][2], acc[1][1]);
    acc[1][1] = MFMA32(aL[1][1], bf[1][3], acc[1][1]);
    PRIO(0); BAR();

    // ---------- phase 2: a[2..3][0..3] (8 reads); stage B0(t+2)
    aH[0][0] = AK(L, 2, 0); aH[0][1] = AK(L, 2, 1);
    aH[0][2] = AK(L, 2, 2); aH[0][3] = AK(L, 2, 3);
    aH[1][0] = AK(L, 3, 0); aH[1][1] = AK(L, 3, 1);
    aH[1][2] = AK(L, 3, 2); aH[1][3] = AK(L, 3, 3);
    if (t + 2 < NT) stage(1, 0, t + 2);
    BAR(); LGKM0(); PRIO(1);
    acc[2][0] = MFMA32(aH[0][0], bf[0][0], acc[2][0]);
    acc[2][0] = MFMA32(aH[0][1], bf[0][1], acc[2][0]);
    acc[2][1] = MFMA32(aH[0][0], bf[1][0], acc[2][1]);
    acc[2][1] = MFMA32(aH[0][1], bf[1][1], acc[2][1]);
    acc[3][0] = MFMA32(aH[1][0], bf[0][0], acc[3][0]);
    acc[3][0] = MFMA32(aH[1][1], bf[0][1], acc[3][0]);
    acc[3][1] = MFMA32(aH[1][0], bf[1][0], acc[3][1]);
    acc[3][1] = MFMA32(aH[1][1], bf[1][1], acc[3][1]);
    PRIO(0); BAR();

    // ---------- phase 3: stage B1(t+2), A0(t+2); MFMA m23 x n01 x kf23; boundary
    if (t + 2 < NT) { stage(1, 1, t + 2); stage(0, 0, t + 2); }
    BAR(); PRIO(1);
    acc[2][0] = MFMA32(aH[0][2], bf[0][2], acc[2][0]);
    acc[2][0] = MFMA32(aH[0][3], bf[0][3], acc[2][0]);
    acc[2][1] = MFMA32(aH[0][2], bf[1][2], acc[2][1]);
    acc[2][1] = MFMA32(aH[0][3], bf[1][3], acc[2][1]);
    acc[3][0] = MFMA32(aH[1][2], bf[0][2], acc[3][0]);
    acc[3][0] = MFMA32(aH[1][3], bf[0][3], acc[3][0]);
    acc[3][1] = MFMA32(aH[1][2], bf[1][2], acc[3][1]);
    acc[3][1] = MFMA32(aH[1][3], bf[1][3], acc[3][1]);
    PRIO(0);
    if (t < NT - 2) { VMCNT6(); } else { VMCNT0(); }
    BAR();
  }

  // epilogue: 32x32 C/D layout col=lane&31, row=(r&3)+8*(r>>2)+4*(lane>>5)  [m74/m101]
  float* Cp = C + (size_t)(bm * BM + wr * 128) * N_OUT + bn * BN + wc * 64;
  #pragma unroll
  for (int m = 0; m < 4; ++m)
    #pragma unroll
    for (int n = 0; n < 2; ++n)
      #pragma unroll
      for (int r = 0; r < 16; ++r) {
        const int row = m * 32 + (r & 3) + 8 * (r >> 2) + 4 * hi;
        Cp[(size_t)row * N_OUT + n * 32 + l5] = acc[m][n][r];
      }
}

// ---------------- fallback (ws too small): fp32 LDS-tiled, correct but slow --
__global__ __launch_bounds__(256) void fb_gemm(const float* __restrict__ x,
                                               const float* __restrict__ W,
                                               float* __restrict__ y) {
  __shared__ float xs[32][33];
  __shared__ float ws[32][33];
  const int bx = blockIdx.x;
  const int by = blockIdx.y;
  const int tx = threadIdx.x & 31;
  const int ty = threadIdx.x >> 5;
  float acc[4] = {0.f, 0.f, 0.f, 0.f};
  for (int k0 = 0; k0 < K_IN; k0 += 32) {
    #pragma unroll
    for (int i = 0; i < 4; ++i) {
      int r = ty + i * 8;
      xs[r][tx] = x[(size_t)(by * 32 + r) * K_IN + k0 + tx];
      float wv = W[(size_t)(bx * 32 + r) * K_IN + k0 + tx];
      ws[r][tx] = wv > 0.f ? 1.f : (wv < 0.f ? -1.f : 0.f);
    }
    __syncthreads();
    #pragma unroll
    for (int i = 0; i < 4; ++i) {
      int r = ty + i * 8;
      float s = acc[i];
      #pragma unroll
      for (int k = 0; k < 32; ++k) s += xs[r][k] * ws[tx][k];
      acc[i] = s;
    }
    __syncthreads();
  }
  #pragma unroll
  for (int i = 0; i < 4; ++i)
    y[(size_t)(by * 32 + ty + i * 8) * N_OUT + bx * 32 + tx] = acc[i];
}

extern "C" void kernel_launch(void* const* d_in, const int* in_sizes, int n_in,
                              void* d_out, int out_size, void* d_ws, size_t ws_size,
                              hipStream_t stream) {
  const float* x = (const float*)d_in[0];   // [8192, 4096]
  const float* W = (const float*)d_in[1];   // [4096, 4096]
  float* y = (float*)d_out;                 // [8192, 4096]

  const size_t need = ((size_t)M_TOK * K_IN + (size_t)N_OUT * K_IN) * 2;
  if (ws_size >= need) {
    __bf16* xb = (__bf16*)d_ws;
    __bf16* wb = xb + (size_t)M_TOK * K_IN;
    cvt_x_bf16<<<2048, 256, 0, stream>>>((const float4*)x, (ushort4*)xb, M_TOK * K_IN / 4);
    sgn_w_bf16<<<2048, 256, 0, stream>>>((const float4*)W, (ushort4*)wb, N_OUT * K_IN / 4);
    bin_gemm256<<<(M_TOK / BM) * (N_OUT / BN), 512, 0, stream>>>(xb, wb, y);
  } else {
    dim3 g(N_OUT / 32, M_TOK / 32);
    fb_gemm<<<g, 256, 0, stream>>>(x, W, y);
  }
}

// Round 4
// 298.588 us; speedup vs baseline: 1.0494x; 1.0494x over previous
//
#include <hip/hip_runtime.h>
#include <hip/hip_bf16.h>
#include <stdint.h>

#define M_TOK 8192
#define N_OUT 4096
#define K_IN  4096

#define BM 256
#define BN 256
#define BK 64
#define NT (K_IN / BK)   // 64 K-tiles

typedef __attribute__((ext_vector_type(8))) __bf16 bf16x8;
typedef __attribute__((ext_vector_type(4))) float  f32x4;

#define AS1 __attribute__((address_space(1)))
#define AS3 __attribute__((address_space(3)))
#define GLOAD_LDS16(g, l) \
  __builtin_amdgcn_global_load_lds((AS1 void*)(g), (AS3 void*)(l), 16, 0, 0)

#define BAR()    __builtin_amdgcn_s_barrier()
#define LGKM0()  do { asm volatile("s_waitcnt lgkmcnt(0)" ::: "memory"); \
                      __builtin_amdgcn_sched_barrier(0); } while (0)
#define LGKM8()  asm volatile("s_waitcnt lgkmcnt(8)" ::: "memory")
#define VMCNT8() asm volatile("s_waitcnt vmcnt(8)" ::: "memory")
#define VMCNT0() asm volatile("s_waitcnt vmcnt(0)" ::: "memory")
#define PRIO(p)  __builtin_amdgcn_s_setprio(p)
#define MFMA16(a, b, c) __builtin_amdgcn_mfma_f32_16x16x32_bf16((a), (b), (c), 0, 0, 0)

// ---------------- prep: x fp32 -> bf16 (RNE via fptrunc) ----------------
__global__ __launch_bounds__(256) void cvt_x_bf16(const float4* __restrict__ x,
                                                  ushort4* __restrict__ o, int n4) {
  int i = blockIdx.x * blockDim.x + threadIdx.x;
  int stride = gridDim.x * blockDim.x;
  for (; i < n4; i += stride) {
    float4 v = x[i];
    ushort4 r;
    r.x = __builtin_bit_cast(unsigned short, (__bf16)v.x);
    r.y = __builtin_bit_cast(unsigned short, (__bf16)v.y);
    r.z = __builtin_bit_cast(unsigned short, (__bf16)v.z);
    r.w = __builtin_bit_cast(unsigned short, (__bf16)v.w);
    o[i] = r;
  }
}

// ---------------- prep: W fp32 -> sign in bf16 ----------------
__global__ __launch_bounds__(256) void sgn_w_bf16(const float4* __restrict__ w,
                                                  ushort4* __restrict__ o, int n4) {
  int i = blockIdx.x * blockDim.x + threadIdx.x;
  int stride = gridDim.x * blockDim.x;
  for (; i < n4; i += stride) {
    float4 v = w[i];
    ushort4 r;
    r.x = v.x > 0.f ? 0x3F80 : (v.x < 0.f ? 0xBF80 : 0);
    r.y = v.y > 0.f ? 0x3F80 : (v.y < 0.f ? 0xBF80 : 0);
    r.z = v.z > 0.f ? 0x3F80 : (v.z < 0.f ? 0xBF80 : 0);
    r.w = v.w > 0.f ? 0x3F80 : (v.w < 0.f ? 0xBF80 : 0);
    o[i] = r;
  }
}

// ======== 256x256 8-phase GEMM (16x16x32): C = A[M][K] * B[N][K]^T ========
// 8 waves (2Mx4N), per-wave 128x64 out, BK=64, 128 KiB LDS double-buffer.
// Phase quadrants per K-tile: p0 m0-3 x n0-1, p1 m0-3 x n2-3, p2 m4-7 x n0-1,
// p3 m4-7 x n2-3 (16 MFMA each; reads 12/4/8/0).
// Staging: ALL of tile t+2 issues during tile t — B halves at p2 (B region dead
// after p1 barrier), A halves at p3 (A dead after p2 barrier). Per-wave 8 loads
// per tile, so boundary wait = vmcnt(8): drains tile t+1's loads, leaves t+2's
// in flight (~5-6 phase lead vs ~4 in round 2).
__global__ __launch_bounds__(512, 2) void bin_gemm256(const __bf16* __restrict__ A,
                                                      const __bf16* __restrict__ B,
                                                      float* __restrict__ C) {
  __shared__ char lds[131072];   // 2 buf x (A 32KB + B 32KB)

  const int tid  = threadIdx.x;
  const int w    = tid >> 6;
  const int lane = tid & 63;
  const int lr   = lane & 15;    // fragment row/col
  const int lk   = lane >> 4;    // k-group 0..3
  const int wr   = w >> 2;       // wave row 0..1  (128 rows each)
  const int wc   = w & 3;        // wave col 0..3  (64 cols each)

  const int bm = blockIdx.x >> 4;     // M/256 = 32
  const int bn = blockIdx.x & 15;     // N/256 = 16

  const char* Ag = (const char*)(A + (size_t)bm * BM * K_IN);
  const char* Bg = (const char*)(B + (size_t)bn * BN * K_IN);

  // staging: linear LDS dest + inverse-swizzled global source (rule #21).
  // chunk c of a 128-row half: row r=c>>3, source slot (c^r)&7
  const int c0 = w * 128 + lane;
  const int c1 = c0 + 64;
  const int r0 = c0 >> 3, r1 = c1 >> 3;
  const size_t g0 = (size_t)r0 * (K_IN * 2) + (size_t)(((c0 ^ r0) & 7) << 4);
  const size_t g1 = (size_t)r1 * (K_IN * 2) + (size_t)(((c1 ^ r1) & 7) << 4);
  const int ldsw = w * 128 * 16;

  auto stage = [&](int mat, int half, int tt) {
    const char* g = (mat ? Bg : Ag) + (size_t)half * (128 * K_IN * 2)
                                    + (size_t)tt * (BK * 2);
    char* l = &lds[((tt & 1) << 16) + (mat << 15) + (half << 14) + ldsw];
    GLOAD_LDS16(g + g0, l);
    GLOAD_LDS16(g + g1, l + 1024);
  };

  // fragment reads (swizzled): (row)*128 + ((s*64 + lk*16) ^ ((row&7)<<4)),
  // row&7 == lr&7 for all fragments (16-row strides).
  const int swz   = (lr & 7) << 4;
  const int a_row = (wr * 128 + lr) * 128;
  const int b_row = 32768 + (wc * 64 + lr) * 128;
  const int k0 = (lk * 16) ^ swz;
  const int k1 = (64 + lk * 16) ^ swz;

  f32x4 acc[8][4];
  #pragma unroll
  for (int m = 0; m < 8; ++m)
    #pragma unroll
    for (int n = 0; n < 4; ++n) { f32x4 z = {0.f,0.f,0.f,0.f}; acc[m][n] = z; }

  // prologue: tile 0 (8 loads) then tile 1 (8 loads); wait tile 0 complete.
  stage(0, 0, 0); stage(0, 1, 0); stage(1, 0, 0); stage(1, 1, 0);
  stage(0, 0, 1); stage(0, 1, 1); stage(1, 0, 1); stage(1, 1, 1);
  VMCNT8();
  BAR();

  for (int t = 0; t < NT; ++t) {
    const char* L = &lds[(size_t)(t & 1) << 16];
    bf16x8 aF[4][2], aS[4][2], bF[4][2];

    // ---------- phase 0: read a[0..3], b[0..1] (12 reads); MFMA m0-3 x n0-1
    #pragma unroll
    for (int m = 0; m < 4; ++m) {
      aF[m][0] = *(const bf16x8*)(L + a_row + m * 2048 + k0);
      aF[m][1] = *(const bf16x8*)(L + a_row + m * 2048 + k1);
    }
    #pragma unroll
    for (int n = 0; n < 2; ++n) {
      bF[n][0] = *(const bf16x8*)(L + b_row + n * 2048 + k0);
      bF[n][1] = *(const bf16x8*)(L + b_row + n * 2048 + k1);
    }
    LGKM8();
    BAR(); LGKM0(); PRIO(1);
    #pragma unroll
    for (int m = 0; m < 4; ++m)
      #pragma unroll
      for (int n = 0; n < 2; ++n) {
        acc[m][n] = MFMA16(aF[m][0], bF[n][0], acc[m][n]);
        acc[m][n] = MFMA16(aF[m][1], bF[n][1], acc[m][n]);
      }
    PRIO(0); BAR();

    // ---------- phase 1: read b[2..3] (4 reads); MFMA m0-3 x n2-3
    #pragma unroll
    for (int n = 2; n < 4; ++n) {
      bF[n][0] = *(const bf16x8*)(L + b_row + n * 2048 + k0);
      bF[n][1] = *(const bf16x8*)(L + b_row + n * 2048 + k1);
    }
    BAR(); LGKM0(); PRIO(1);
    #pragma unroll
    for (int m = 0; m < 4; ++m)
      #pragma unroll
      for (int n = 2; n < 4; ++n) {
        acc[m][n] = MFMA16(aF[m][0], bF[n][0], acc[m][n]);
        acc[m][n] = MFMA16(aF[m][1], bF[n][1], acc[m][n]);
      }
    PRIO(0); BAR();

    // ---------- phase 2: read a[4..7] (8 reads); stage B0,B1(t+2); MFMA m4-7 x n0-1
    #pragma unroll
    for (int m = 0; m < 4; ++m) {
      aS[m][0] = *(const bf16x8*)(L + a_row + 8192 + m * 2048 + k0);
      aS[m][1] = *(const bf16x8*)(L + a_row + 8192 + m * 2048 + k1);
    }
    if (t + 2 < NT) { stage(1, 0, t + 2); stage(1, 1, t + 2); }
    BAR(); LGKM0(); PRIO(1);
    #pragma unroll
    for (int m = 0; m < 4; ++m)
      #pragma unroll
      for (int n = 0; n < 2; ++n) {
        acc[4 + m][n] = MFMA16(aS[m][0], bF[n][0], acc[4 + m][n]);
        acc[4 + m][n] = MFMA16(aS[m][1], bF[n][1], acc[4 + m][n]);
      }
    PRIO(0); BAR();

    // ---------- phase 3: stage A0,A1(t+2); MFMA m4-7 x n2-3; boundary vmcnt
    if (t + 2 < NT) { stage(0, 0, t + 2); stage(0, 1, t + 2); }
    BAR(); PRIO(1);
    #pragma unroll
    for (int m = 0; m < 4; ++m)
      #pragma unroll
      for (int n = 2; n < 4; ++n) {
        acc[4 + m][n] = MFMA16(aS[m][0], bF[n][0], acc[4 + m][n]);
        acc[4 + m][n] = MFMA16(aS[m][1], bF[n][1], acc[4 + m][n]);
      }
    PRIO(0);
    if (t < NT - 2) { VMCNT8(); } else { VMCNT0(); }
    BAR();
  }

  // epilogue: C/D layout col=lane&15, row=(lane>>4)*4+reg  [m89-verified]
  float* Cp = C + (size_t)(bm * BM + wr * 128) * N_OUT + bn * BN + wc * 64;
  #pragma unroll
  for (int m = 0; m < 8; ++m)
    #pragma unroll
    for (int n = 0; n < 4; ++n)
      #pragma unroll
      for (int j = 0; j < 4; ++j)
        Cp[(size_t)(m * 16 + lk * 4 + j) * N_OUT + n * 16 + lr] = acc[m][n][j];
}

// ---------------- fallback (ws too small): fp32 LDS-tiled, correct but slow --
__global__ __launch_bounds__(256) void fb_gemm(const float* __restrict__ x,
                                               const float* __restrict__ W,
                                               float* __restrict__ y) {
  __shared__ float xs[32][33];
  __shared__ float ws[32][33];
  const int bx = blockIdx.x;
  const int by = blockIdx.y;
  const int tx = threadIdx.x & 31;
  const int ty = threadIdx.x >> 5;
  float acc[4] = {0.f, 0.f, 0.f, 0.f};
  for (int k0 = 0; k0 < K_IN; k0 += 32) {
    #pragma unroll
    for (int i = 0; i < 4; ++i) {
      int r = ty + i * 8;
      xs[r][tx] = x[(size_t)(by * 32 + r) * K_IN + k0 + tx];
      float wv = W[(size_t)(bx * 32 + r) * K_IN + k0 + tx];
      ws[r][tx] = wv > 0.f ? 1.f : (wv < 0.f ? -1.f : 0.f);
    }
    __syncthreads();
    #pragma unroll
    for (int i = 0; i < 4; ++i) {
      int r = ty + i * 8;
      float s = acc[i];
      #pragma unroll
      for (int k = 0; k < 32; ++k) s += xs[r][k] * ws[tx][k];
      acc[i] = s;
    }
    __syncthreads();
  }
  #pragma unroll
  for (int i = 0; i < 4; ++i)
    y[(size_t)(by * 32 + ty + i * 8) * N_OUT + bx * 32 + tx] = acc[i];
}

extern "C" void kernel_launch(void* const* d_in, const int* in_sizes, int n_in,
                              void* d_out, int out_size, void* d_ws, size_t ws_size,
                              hipStream_t stream) {
  const float* x = (const float*)d_in[0];   // [8192, 4096]
  const float* W = (const float*)d_in[1];   // [4096, 4096]
  float* y = (float*)d_out;                 // [8192, 4096]

  const size_t need = ((size_t)M_TOK * K_IN + (size_t)N_OUT * K_IN) * 2;
  if (ws_size >= need) {
    __bf16* xb = (__bf16*)d_ws;
    __bf16* wb = xb + (size_t)M_TOK * K_IN;
    cvt_x_bf16<<<2048, 256, 0, stream>>>((const float4*)x, (ushort4*)xb, M_TOK * K_IN / 4);
    sgn_w_bf16<<<2048, 256, 0, stream>>>((const float4*)W, (ushort4*)wb, N_OUT * K_IN / 4);
    bin_gemm256<<<(M_TOK / BM) * (N_OUT / BN), 512, 0, stream>>>(xb, wb, y);
  } else {
    dim3 g(N_OUT / 32, M_TOK / 32);
    fb_gemm<<<g, 256, 0, stream>>>(x, W, y);
  }
}

// Round 5
// 282.683 us; speedup vs baseline: 1.1084x; 1.0563x over previous
//
#include <hip/hip_runtime.h>
#include <hip/hip_bf16.h>
#include <stdint.h>

#define M_TOK 8192
#define N_OUT 4096
#define K_IN  4096

#define BM 256
#define BN 256
#define BK 64
#define NT (K_IN / BK)   // 64 K-tiles

typedef __attribute__((ext_vector_type(8))) __bf16 bf16x8;
typedef __attribute__((ext_vector_type(4))) float  f32x4;

#define AS1 __attribute__((address_space(1)))
#define AS3 __attribute__((address_space(3)))
#define GLOAD_LDS16(g, l) \
  __builtin_amdgcn_global_load_lds((AS1 void*)(g), (AS3 void*)(l), 16, 0, 0)

#define BAR()    __builtin_amdgcn_s_barrier()
#define LGKM0()  asm volatile("s_waitcnt lgkmcnt(0)" ::: "memory")
#define VMCNT8() asm volatile("s_waitcnt vmcnt(8)" ::: "memory")
#define VMCNT0() asm volatile("s_waitcnt vmcnt(0)" ::: "memory")
#define PRIO(p)  __builtin_amdgcn_s_setprio(p)
#define MFMA16(a, b, c) __builtin_amdgcn_mfma_f32_16x16x32_bf16((a), (b), (c), 0, 0, 0)

// ---------------- prep: x fp32 -> bf16 (RNE via fptrunc) ----------------
__global__ __launch_bounds__(256) void cvt_x_bf16(const float4* __restrict__ x,
                                                  ushort4* __restrict__ o, int n4) {
  int i = blockIdx.x * blockDim.x + threadIdx.x;
  int stride = gridDim.x * blockDim.x;
  for (; i < n4; i += stride) {
    float4 v = x[i];
    ushort4 r;
    r.x = __builtin_bit_cast(unsigned short, (__bf16)v.x);
    r.y = __builtin_bit_cast(unsigned short, (__bf16)v.y);
    r.z = __builtin_bit_cast(unsigned short, (__bf16)v.z);
    r.w = __builtin_bit_cast(unsigned short, (__bf16)v.w);
    o[i] = r;
  }
}

// ---------------- prep: W fp32 -> sign in bf16 ----------------
__global__ __launch_bounds__(256) void sgn_w_bf16(const float4* __restrict__ w,
                                                  ushort4* __restrict__ o, int n4) {
  int i = blockIdx.x * blockDim.x + threadIdx.x;
  int stride = gridDim.x * blockDim.x;
  for (; i < n4; i += stride) {
    float4 v = w[i];
    ushort4 r;
    r.x = v.x > 0.f ? 0x3F80 : (v.x < 0.f ? 0xBF80 : 0);
    r.y = v.y > 0.f ? 0x3F80 : (v.y < 0.f ? 0xBF80 : 0);
    r.z = v.z > 0.f ? 0x3F80 : (v.z < 0.f ? 0xBF80 : 0);
    r.w = v.w > 0.f ? 0x3F80 : (v.w < 0.f ? 0xBF80 : 0);
    o[i] = r;
  }
}

// ======== 256x256 GEMM, 2 relaxed regions/K-tile: C = A[M][K] * B[N][K]^T ====
// 8 waves (2Mx4N), per-wave 128x64 out, BK=64, 128 KiB LDS double-buffer.
// Region 1: all 24 ds_read_b128 + 32 MFMA (m0-3 x n0-3) — compiler-scheduled,
//   reads/MFMAs interleave as deps resolve.
// mid {lgkmcnt(0); barrier}: every wave's reads retired -> whole tile region
//   (A and B) is dead; safe to overwrite.
// Region 2: stage ALL of tile t+2 (8 gloads, into the CURRENT buffer index
//   (t+2)&1 == t&1 — legal because of the mid-barrier deadness) + 32 pure-reg
//   MFMA (m4-7 x n0-3) under setprio; staging latency hides under MFMA.
// Boundary: counted vmcnt(8) (drains t+1's loads, leaves t+2's in flight) + BAR.
__global__ __launch_bounds__(512, 2) void bin_gemm256(const __bf16* __restrict__ A,
                                                      const __bf16* __restrict__ B,
                                                      float* __restrict__ C) {
  __shared__ char lds[131072];   // 2 buf x (A 32KB + B 32KB)

  const int tid  = threadIdx.x;
  const int w    = tid >> 6;
  const int lane = tid & 63;
  const int lr   = lane & 15;    // fragment row/col
  const int lk   = lane >> 4;    // k-group 0..3
  const int wr   = w >> 2;       // wave row 0..1  (128 rows each)
  const int wc   = w & 3;        // wave col 0..3  (64 cols each)

  const int bm = blockIdx.x >> 4;     // M/256 = 32
  const int bn = blockIdx.x & 15;     // N/256 = 16

  const char* Ag = (const char*)(A + (size_t)bm * BM * K_IN);
  const char* Bg = (const char*)(B + (size_t)bn * BN * K_IN);

  // staging: linear LDS dest + inverse-swizzled global source (rule #21).
  // chunk c of a 128-row half: row r=c>>3, source slot (c^r)&7
  const int c0 = w * 128 + lane;
  const int c1 = c0 + 64;
  const int r0 = c0 >> 3, r1 = c1 >> 3;
  const size_t g0 = (size_t)r0 * (K_IN * 2) + (size_t)(((c0 ^ r0) & 7) << 4);
  const size_t g1 = (size_t)r1 * (K_IN * 2) + (size_t)(((c1 ^ r1) & 7) << 4);
  const int ldsw = w * 128 * 16;

  auto stage = [&](int mat, int half, int tt) {
    const char* g = (mat ? Bg : Ag) + (size_t)half * (128 * K_IN * 2)
                                    + (size_t)tt * (BK * 2);
    char* l = &lds[((tt & 1) << 16) + (mat << 15) + (half << 14) + ldsw];
    GLOAD_LDS16(g + g0, l);
    GLOAD_LDS16(g + g1, l + 1024);
  };

  // fragment reads (swizzled): (row)*128 + ((s*64 + lk*16) ^ ((row&7)<<4)),
  // row&7 == lr&7 for all fragments (16-row strides).
  const int swz   = (lr & 7) << 4;
  const int a_row = (wr * 128 + lr) * 128;
  const int b_row = 32768 + (wc * 64 + lr) * 128;
  const int k0 = (lk * 16) ^ swz;
  const int k1 = (64 + lk * 16) ^ swz;

  f32x4 acc[8][4];
  #pragma unroll
  for (int m = 0; m < 8; ++m)
    #pragma unroll
    for (int n = 0; n < 4; ++n) { f32x4 z = {0.f,0.f,0.f,0.f}; acc[m][n] = z; }

  // prologue: tile 0 (8 loads) then tile 1 (8 loads); wait tile 0 complete.
  stage(0, 0, 0); stage(0, 1, 0); stage(1, 0, 0); stage(1, 1, 0);
  stage(0, 0, 1); stage(0, 1, 1); stage(1, 0, 1); stage(1, 1, 1);
  VMCNT8();
  BAR();

  for (int t = 0; t < NT; ++t) {
    const char* L = &lds[(size_t)(t & 1) << 16];
    bf16x8 aF[4][2], aS[4][2], bF[4][2];

    // ================= region 1: 24 reads + MFMA m0-3 x n0-3 ==============
    #pragma unroll
    for (int m = 0; m < 4; ++m) {
      aF[m][0] = *(const bf16x8*)(L + a_row + m * 2048 + k0);
      aF[m][1] = *(const bf16x8*)(L + a_row + m * 2048 + k1);
    }
    #pragma unroll
    for (int n = 0; n < 4; ++n) {
      bF[n][0] = *(const bf16x8*)(L + b_row + n * 2048 + k0);
      bF[n][1] = *(const bf16x8*)(L + b_row + n * 2048 + k1);
    }
    // first half of region-1 MFMAs (m0-1)
    #pragma unroll
    for (int m = 0; m < 2; ++m)
      #pragma unroll
      for (int n = 0; n < 4; ++n) {
        acc[m][n] = MFMA16(aF[m][0], bF[n][0], acc[m][n]);
        acc[m][n] = MFMA16(aF[m][1], bF[n][1], acc[m][n]);
      }
    // aS reads (needed only in region 2) — latency hides under MFMAs
    #pragma unroll
    for (int m = 0; m < 4; ++m) {
      aS[m][0] = *(const bf16x8*)(L + a_row + 8192 + m * 2048 + k0);
      aS[m][1] = *(const bf16x8*)(L + a_row + 8192 + m * 2048 + k1);
    }
    // second half of region-1 MFMAs (m2-3)
    #pragma unroll
    for (int m = 2; m < 4; ++m)
      #pragma unroll
      for (int n = 0; n < 4; ++n) {
        acc[m][n] = MFMA16(aF[m][0], bF[n][0], acc[m][n]);
        acc[m][n] = MFMA16(aF[m][1], bF[n][1], acc[m][n]);
      }

    // ---- mid: per-wave read drain + barrier => tile regions dead
    LGKM0();
    BAR();

    // ================= region 2: stage t+2 + MFMA m4-7 x n0-3 =============
    if (t + 2 < NT) {
      stage(1, 0, t + 2); stage(1, 1, t + 2);   // B halves
      stage(0, 0, t + 2); stage(0, 1, t + 2);   // A halves
    }
    PRIO(1);
    #pragma unroll
    for (int m = 0; m < 4; ++m)
      #pragma unroll
      for (int n = 0; n < 4; ++n) {
        acc[4 + m][n] = MFMA16(aS[m][0], bF[n][0], acc[4 + m][n]);
        acc[4 + m][n] = MFMA16(aS[m][1], bF[n][1], acc[4 + m][n]);
      }
    PRIO(0);

    // ---- boundary: tile t+1's loads must be complete; t+2's stay in flight
    if (t < NT - 2) { VMCNT8(); } else { VMCNT0(); }
    BAR();
  }

  // epilogue: C/D layout col=lane&15, row=(lane>>4)*4+reg  [m89-verified]
  float* Cp = C + (size_t)(bm * BM + wr * 128) * N_OUT + bn * BN + wc * 64;
  #pragma unroll
  for (int m = 0; m < 8; ++m)
    #pragma unroll
    for (int n = 0; n < 4; ++n)
      #pragma unroll
      for (int j = 0; j < 4; ++j)
        Cp[(size_t)(m * 16 + lk * 4 + j) * N_OUT + n * 16 + lr] = acc[m][n][j];
}

// ---------------- fallback (ws too small): fp32 LDS-tiled, correct but slow --
__global__ __launch_bounds__(256) void fb_gemm(const float* __restrict__ x,
                                               const float* __restrict__ W,
                                               float* __restrict__ y) {
  __shared__ float xs[32][33];
  __shared__ float ws[32][33];
  const int bx = blockIdx.x;
  const int by = blockIdx.y;
  const int tx = threadIdx.x & 31;
  const int ty = threadIdx.x >> 5;
  float acc[4] = {0.f, 0.f, 0.f, 0.f};
  for (int k0 = 0; k0 < K_IN; k0 += 32) {
    #pragma unroll
    for (int i = 0; i < 4; ++i) {
      int r = ty + i * 8;
      xs[r][tx] = x[(size_t)(by * 32 + r) * K_IN + k0 + tx];
      float wv = W[(size_t)(bx * 32 + r) * K_IN + k0 + tx];
      ws[r][tx] = wv > 0.f ? 1.f : (wv < 0.f ? -1.f : 0.f);
    }
    __syncthreads();
    #pragma unroll
    for (int i = 0; i < 4; ++i) {
      int r = ty + i * 8;
      float s = acc[i];
      #pragma unroll
      for (int k = 0; k < 32; ++k) s += xs[r][k] * ws[tx][k];
      acc[i] = s;
    }
    __syncthreads();
  }
  #pragma unroll
  for (int i = 0; i < 4; ++i)
    y[(size_t)(by * 32 + ty + i * 8) * N_OUT + bx * 32 + tx] = acc[i];
}

extern "C" void kernel_launch(void* const* d_in, const int* in_sizes, int n_in,
                              void* d_out, int out_size, void* d_ws, size_t ws_size,
                              hipStream_t stream) {
  const float* x = (const float*)d_in[0];   // [8192, 4096]
  const float* W = (const float*)d_in[1];   // [4096, 4096]
  float* y = (float*)d_out;                 // [8192, 4096]

  const size_t need = ((size_t)M_TOK * K_IN + (size_t)N_OUT * K_IN) * 2;
  if (ws_size >= need) {
    __bf16* xb = (__bf16*)d_ws;
    __bf16* wb = xb + (size_t)M_TOK * K_IN;
    cvt_x_bf16<<<2048, 256, 0, stream>>>((const float4*)x, (ushort4*)xb, M_TOK * K_IN / 4);
    sgn_w_bf16<<<2048, 256, 0, stream>>>((const float4*)W, (ushort4*)wb, N_OUT * K_IN / 4);
    bin_gemm256<<<(M_TOK / BM) * (N_OUT / BN), 512, 0, stream>>>(xb, wb, y);
  } else {
    dim3 g(N_OUT / 32, M_TOK / 32);
    fb_gemm<<<g, 256, 0, stream>>>(x, W, y);
  }
}

// Round 6
// 182.566 us; speedup vs baseline: 1.7163x; 1.5484x over previous
//
#include <hip/hip_runtime.h>
#include <hip/hip_bf16.h>
#include <stdint.h>

#define M_TOK 8192
#define N_OUT 4096
#define K_IN  4096

#define BM 256
#define BN 256
#define BKB 128            // K-tile depth in BYTES (= 128 i8 elements)
#define NT (K_IN / BKB)    // 32 K-tiles

typedef __attribute__((ext_vector_type(4))) int   i32x4;
typedef __attribute__((ext_vector_type(4))) float f32x4;

#define AS1 __attribute__((address_space(1)))
#define AS3 __attribute__((address_space(3)))
#define GLOAD_LDS16(g, l) \
  __builtin_amdgcn_global_load_lds((AS1 void*)(g), (AS3 void*)(l), 16, 0, 0)

#define BAR()    __builtin_amdgcn_s_barrier()
#define LGKM0()  asm volatile("s_waitcnt lgkmcnt(0)" ::: "memory")
#define VMCNT8() asm volatile("s_waitcnt vmcnt(8)" ::: "memory")
#define VMCNT0() asm volatile("s_waitcnt vmcnt(0)" ::: "memory")
#define PRIO(p)  __builtin_amdgcn_s_setprio(p)
#define MFMAI8(a, b, c) __builtin_amdgcn_mfma_i32_16x16x64_i8((a), (b), (c), 0, 0, 0)

// ---------------- prep: x fp32 -> i8 with per-row scale (RNE) ----------------
// One block per row: 256 threads x 16 elements, kept in registers between the
// absmax pass and the quantize pass (row read exactly once).
__global__ __launch_bounds__(256) void quant_x_i8(const float4* __restrict__ x,
                                                  int4* __restrict__ o,
                                                  float* __restrict__ scales) {
  const int row = blockIdx.x;
  const int t   = threadIdx.x;
  const float4* xr = x + (size_t)row * (K_IN / 4);
  float4 v[4];
  #pragma unroll
  for (int i = 0; i < 4; ++i) v[i] = xr[t * 4 + i];
  float m = 0.f;
  #pragma unroll
  for (int i = 0; i < 4; ++i)
    m = fmaxf(m, fmaxf(fmaxf(fabsf(v[i].x), fabsf(v[i].y)),
                       fmaxf(fabsf(v[i].z), fabsf(v[i].w))));
  #pragma unroll
  for (int off = 32; off; off >>= 1) m = fmaxf(m, __shfl_down(m, off));
  __shared__ float sm[4];
  if ((t & 63) == 0) sm[t >> 6] = m;
  __syncthreads();
  m = fmaxf(fmaxf(sm[0], sm[1]), fmaxf(sm[2], sm[3]));
  const float inv = m > 0.f ? 127.f / m : 0.f;
  if (t == 0) scales[row] = m > 0.f ? m / 127.f : 1.f;
  int q[4];
  #pragma unroll
  for (int i = 0; i < 4; ++i) {
    const int a0 = (int)rintf(v[i].x * inv);
    const int a1 = (int)rintf(v[i].y * inv);
    const int a2 = (int)rintf(v[i].z * inv);
    const int a3 = (int)rintf(v[i].w * inv);
    q[i] = (a0 & 255) | ((a1 & 255) << 8) | ((a2 & 255) << 16) | (a3 << 24);
  }
  o[(size_t)row * (K_IN / 16) + t] = make_int4(q[0], q[1], q[2], q[3]);
}

// ---------------- prep: W fp32 -> sign in i8 {-1, 0, +1} ----------------
__global__ __launch_bounds__(256) void sgn_w_i8(const float4* __restrict__ w,
                                                int4* __restrict__ o, int n16) {
  int i = blockIdx.x * blockDim.x + threadIdx.x;
  int stride = gridDim.x * blockDim.x;
  for (; i < n16; i += stride) {
    int q[4];
    #pragma unroll
    for (int j = 0; j < 4; ++j) {
      float4 v = w[i * 4 + j];
      const int a0 = v.x > 0.f ? 1 : (v.x < 0.f ? -1 : 0);
      const int a1 = v.y > 0.f ? 1 : (v.y < 0.f ? -1 : 0);
      const int a2 = v.z > 0.f ? 1 : (v.z < 0.f ? -1 : 0);
      const int a3 = v.w > 0.f ? 1 : (v.w < 0.f ? -1 : 0);
      q[j] = (a0 & 255) | ((a1 & 255) << 8) | ((a2 & 255) << 16) | (a3 << 24);
    }
    o[i] = make_int4(q[0], q[1], q[2], q[3]);
  }
}

// ======== 256x256 i8 GEMM, 2 relaxed regions/K-tile (round-5 schedule) =======
// C[t][o] = (x_q[t][:] . w_q[o][:]) * scale[t].  i32 accumulate (exact).
// 8 waves (2Mx4N), per-wave 128x64 out, BKB=128 B (=128 i8), 128 KiB LDS dbuf.
// Same byte-level LDS layout/swizzle as the verified bf16 kernel (128 B rows,
// slot XOR (row&7)) -> 0 bank conflicts expected.
__global__ __launch_bounds__(512, 2) void bin_gemm_i8(const char* __restrict__ A,
                                                      const char* __restrict__ B,
                                                      const float* __restrict__ scales,
                                                      float* __restrict__ C) {
  __shared__ char lds[131072];   // 2 buf x (A 32KB + B 32KB)

  const int tid  = threadIdx.x;
  const int w    = tid >> 6;
  const int lane = tid & 63;
  const int lr   = lane & 15;    // fragment row/col
  const int lk   = lane >> 4;    // k-group 0..3 (16 bytes each)
  const int wr   = w >> 2;       // wave row 0..1  (128 rows each)
  const int wc   = w & 3;        // wave col 0..3  (64 cols each)

  const int bm = blockIdx.x >> 4;     // M/256 = 32
  const int bn = blockIdx.x & 15;     // N/256 = 16

  const char* Ag = A + (size_t)bm * BM * K_IN;
  const char* Bg = B + (size_t)bn * BN * K_IN;

  // staging: linear LDS dest + inverse-swizzled global source (rule #21).
  // chunk c (16B) of a 128-row half: row r=c>>3, source slot (c^r)&7.
  const int c0 = w * 128 + lane;
  const int c1 = c0 + 64;
  const int r0 = c0 >> 3, r1 = c1 >> 3;
  const size_t g0 = (size_t)r0 * K_IN + (size_t)(((c0 ^ r0) & 7) << 4);
  const size_t g1 = (size_t)r1 * K_IN + (size_t)(((c1 ^ r1) & 7) << 4);
  const int ldsw = w * 128 * 16;

  auto stage = [&](int mat, int half, int tt) {
    const char* g = (mat ? Bg : Ag) + (size_t)half * (128 * K_IN)
                                    + (size_t)tt * BKB;
    char* l = &lds[((tt & 1) << 16) + (mat << 15) + (half << 14) + ldsw];
    GLOAD_LDS16(g + g0, l);
    GLOAD_LDS16(g + g1, l + 1024);
  };

  // fragment reads (swizzled): (row)*128 + ((ks*64 + lk*16) ^ ((row&7)<<4));
  // row&7 == lr&7 for all fragments (16-row strides).
  const int swz   = (lr & 7) << 4;
  const int a_row = (wr * 128 + lr) * 128;
  const int b_row = 32768 + (wc * 64 + lr) * 128;
  const int k0 = (lk * 16) ^ swz;          // k bytes 0..63
  const int k1 = (64 + lk * 16) ^ swz;     // k bytes 64..127

  i32x4 acc[8][4];
  #pragma unroll
  for (int m = 0; m < 8; ++m)
    #pragma unroll
    for (int n = 0; n < 4; ++n) { i32x4 z = {0, 0, 0, 0}; acc[m][n] = z; }

  // prologue: tile 0 (8 loads) then tile 1 (8 loads); wait tile 0 complete.
  stage(0, 0, 0); stage(0, 1, 0); stage(1, 0, 0); stage(1, 1, 0);
  stage(0, 0, 1); stage(0, 1, 1); stage(1, 0, 1); stage(1, 1, 1);
  VMCNT8();
  BAR();

  for (int t = 0; t < NT; ++t) {
    const char* L = &lds[(size_t)(t & 1) << 16];
    i32x4 aF[4][2], aS[4][2], bF[4][2];

    // ================= region 1: 24 reads + MFMA m0-3 x n0-3 ==============
    #pragma unroll
    for (int m = 0; m < 4; ++m) {
      aF[m][0] = *(const i32x4*)(L + a_row + m * 2048 + k0);
      aF[m][1] = *(const i32x4*)(L + a_row + m * 2048 + k1);
    }
    #pragma unroll
    for (int n = 0; n < 4; ++n) {
      bF[n][0] = *(const i32x4*)(L + b_row + n * 2048 + k0);
      bF[n][1] = *(const i32x4*)(L + b_row + n * 2048 + k1);
    }
    // first half of region-1 MFMAs (m0-1)
    #pragma unroll
    for (int m = 0; m < 2; ++m)
      #pragma unroll
      for (int n = 0; n < 4; ++n) {
        acc[m][n] = MFMAI8(aF[m][0], bF[n][0], acc[m][n]);
        acc[m][n] = MFMAI8(aF[m][1], bF[n][1], acc[m][n]);
      }
    // aS reads (region-2 operands) — latency hides under MFMAs
    #pragma unroll
    for (int m = 0; m < 4; ++m) {
      aS[m][0] = *(const i32x4*)(L + a_row + 8192 + m * 2048 + k0);
      aS[m][1] = *(const i32x4*)(L + a_row + 8192 + m * 2048 + k1);
    }
    // second half of region-1 MFMAs (m2-3)
    #pragma unroll
    for (int m = 2; m < 4; ++m)
      #pragma unroll
      for (int n = 0; n < 4; ++n) {
        acc[m][n] = MFMAI8(aF[m][0], bF[n][0], acc[m][n]);
        acc[m][n] = MFMAI8(aF[m][1], bF[n][1], acc[m][n]);
      }

    // ---- mid: per-wave read drain + barrier => tile regions dead
    LGKM0();
    BAR();

    // ================= region 2: stage t+2 + MFMA m4-7 x n0-3 =============
    if (t + 2 < NT) {
      stage(1, 0, t + 2); stage(1, 1, t + 2);   // B halves
      stage(0, 0, t + 2); stage(0, 1, t + 2);   // A halves
    }
    PRIO(1);
    #pragma unroll
    for (int m = 0; m < 4; ++m)
      #pragma unroll
      for (int n = 0; n < 4; ++n) {
        acc[4 + m][n] = MFMAI8(aS[m][0], bF[n][0], acc[4 + m][n]);
        acc[4 + m][n] = MFMAI8(aS[m][1], bF[n][1], acc[4 + m][n]);
      }
    PRIO(0);

    // ---- boundary: tile t+1's loads complete; t+2's stay in flight
    if (t < NT - 2) { VMCNT8(); } else { VMCNT0(); }
    BAR();
  }

  // epilogue: C/D layout col=lane&15, row=(lane>>4)*4+reg; y = acc * scale[row]
  const int grow0 = bm * BM + wr * 128;
  float scl[8][4];
  #pragma unroll
  for (int m = 0; m < 8; ++m)
    #pragma unroll
    for (int j = 0; j < 4; ++j)
      scl[m][j] = scales[grow0 + m * 16 + lk * 4 + j];

  float* Cp = C + (size_t)grow0 * N_OUT + bn * BN + wc * 64;
  #pragma unroll
  for (int m = 0; m < 8; ++m)
    #pragma unroll
    for (int n = 0; n < 4; ++n)
      #pragma unroll
      for (int j = 0; j < 4; ++j)
        Cp[(size_t)(m * 16 + lk * 4 + j) * N_OUT + n * 16 + lr] =
            (float)acc[m][n][j] * scl[m][j];
}

// ---------------- fallback (ws too small): fp32 LDS-tiled, correct but slow --
__global__ __launch_bounds__(256) void fb_gemm(const float* __restrict__ x,
                                               const float* __restrict__ W,
                                               float* __restrict__ y) {
  __shared__ float xs[32][33];
  __shared__ float ws[32][33];
  const int bx = blockIdx.x;
  const int by = blockIdx.y;
  const int tx = threadIdx.x & 31;
  const int ty = threadIdx.x >> 5;
  float acc[4] = {0.f, 0.f, 0.f, 0.f};
  for (int k0 = 0; k0 < K_IN; k0 += 32) {
    #pragma unroll
    for (int i = 0; i < 4; ++i) {
      int r = ty + i * 8;
      xs[r][tx] = x[(size_t)(by * 32 + r) * K_IN + k0 + tx];
      float wv = W[(size_t)(bx * 32 + r) * K_IN + k0 + tx];
      ws[r][tx] = wv > 0.f ? 1.f : (wv < 0.f ? -1.f : 0.f);
    }
    __syncthreads();
    #pragma unroll
    for (int i = 0; i < 4; ++i) {
      int r = ty + i * 8;
      float s = acc[i];
      #pragma unroll
      for (int k = 0; k < 32; ++k) s += xs[r][k] * ws[tx][k];
      acc[i] = s;
    }
    __syncthreads();
  }
  #pragma unroll
  for (int i = 0; i < 4; ++i)
    y[(size_t)(by * 32 + ty + i * 8) * N_OUT + bx * 32 + tx] = acc[i];
}

extern "C" void kernel_launch(void* const* d_in, const int* in_sizes, int n_in,
                              void* d_out, int out_size, void* d_ws, size_t ws_size,
                              hipStream_t stream) {
  const float* x = (const float*)d_in[0];   // [8192, 4096]
  const float* W = (const float*)d_in[1];   // [4096, 4096]
  float* y = (float*)d_out;                 // [8192, 4096]

  const size_t need = (size_t)M_TOK * K_IN + (size_t)N_OUT * K_IN
                    + (size_t)M_TOK * sizeof(float);
  if (ws_size >= need) {
    char*  xq = (char*)d_ws;
    char*  wq = xq + (size_t)M_TOK * K_IN;
    float* sc = (float*)(wq + (size_t)N_OUT * K_IN);
    quant_x_i8<<<M_TOK, 256, 0, stream>>>((const float4*)x, (int4*)xq, sc);
    sgn_w_i8<<<2048, 256, 0, stream>>>((const float4*)W, (int4*)wq,
                                       N_OUT * K_IN / 16);
    bin_gemm_i8<<<(M_TOK / BM) * (N_OUT / BN), 512, 0, stream>>>(xq, wq, sc, y);
  } else {
    dim3 g(N_OUT / 32, M_TOK / 32);
    fb_gemm<<<g, 256, 0, stream>>>(x, W, y);
  }
}

// Round 7
// 177.768 us; speedup vs baseline: 1.7626x; 1.0270x over previous
//
#include <hip/hip_runtime.h>
#include <hip/hip_bf16.h>
#include <stdint.h>

#define M_TOK 8192
#define N_OUT 4096
#define K_IN  4096

#define BM 256
#define BN 256
#define BKB 128            // K-tile depth in BYTES (= 128 i8 elements)
#define NT (K_IN / BKB)    // 32 K-tiles

typedef __attribute__((ext_vector_type(4))) int   i32x4;
typedef __attribute__((ext_vector_type(4))) float f32x4;

#define AS1 __attribute__((address_space(1)))
#define AS3 __attribute__((address_space(3)))
#define GLOAD_LDS16(g, l) \
  __builtin_amdgcn_global_load_lds((AS1 void*)(g), (AS3 void*)(l), 16, 0, 0)

#define BAR()     __builtin_amdgcn_s_barrier()
#define WAITALL() asm volatile("s_waitcnt vmcnt(0) lgkmcnt(0)" ::: "memory")
#define VMCNT8()  asm volatile("s_waitcnt vmcnt(8)" ::: "memory")
#define PRIO(p)   __builtin_amdgcn_s_setprio(p)
#define MFMAI8(a, b, c) __builtin_amdgcn_mfma_i32_16x16x64_i8((a), (b), (c), 0, 0, 0)

// ---------------- prep: x fp32 -> i8 with per-row scale (RNE) ----------------
__global__ __launch_bounds__(256) void quant_x_i8(const float4* __restrict__ x,
                                                  int4* __restrict__ o,
                                                  float* __restrict__ scales) {
  const int row = blockIdx.x;
  const int t   = threadIdx.x;
  const float4* xr = x + (size_t)row * (K_IN / 4);
  float4 v[4];
  #pragma unroll
  for (int i = 0; i < 4; ++i) v[i] = xr[t * 4 + i];
  float m = 0.f;
  #pragma unroll
  for (int i = 0; i < 4; ++i)
    m = fmaxf(m, fmaxf(fmaxf(fabsf(v[i].x), fabsf(v[i].y)),
                       fmaxf(fabsf(v[i].z), fabsf(v[i].w))));
  #pragma unroll
  for (int off = 32; off; off >>= 1) m = fmaxf(m, __shfl_down(m, off));
  __shared__ float sm[4];
  if ((t & 63) == 0) sm[t >> 6] = m;
  __syncthreads();
  m = fmaxf(fmaxf(sm[0], sm[1]), fmaxf(sm[2], sm[3]));
  const float inv = m > 0.f ? 127.f / m : 0.f;
  if (t == 0) scales[row] = m > 0.f ? m / 127.f : 1.f;
  int q[4];
  #pragma unroll
  for (int i = 0; i < 4; ++i) {
    const int a0 = (int)rintf(v[i].x * inv);
    const int a1 = (int)rintf(v[i].y * inv);
    const int a2 = (int)rintf(v[i].z * inv);
    const int a3 = (int)rintf(v[i].w * inv);
    q[i] = (a0 & 255) | ((a1 & 255) << 8) | ((a2 & 255) << 16) | (a3 << 24);
  }
  o[(size_t)row * (K_IN / 16) + t] = make_int4(q[0], q[1], q[2], q[3]);
}

// ---------------- prep: W fp32 -> sign in i8 {-1, 0, +1} ----------------
__global__ __launch_bounds__(256) void sgn_w_i8(const float4* __restrict__ w,
                                                int4* __restrict__ o, int n16) {
  int i = blockIdx.x * blockDim.x + threadIdx.x;
  int stride = gridDim.x * blockDim.x;
  for (; i < n16; i += stride) {
    int q[4];
    #pragma unroll
    for (int j = 0; j < 4; ++j) {
      float4 v = w[i * 4 + j];
      const int a0 = v.x > 0.f ? 1 : (v.x < 0.f ? -1 : 0);
      const int a1 = v.y > 0.f ? 1 : (v.y < 0.f ? -1 : 0);
      const int a2 = v.z > 0.f ? 1 : (v.z < 0.f ? -1 : 0);
      const int a3 = v.w > 0.f ? 1 : (v.w < 0.f ? -1 : 0);
      q[j] = (a0 & 255) | ((a1 & 255) << 8) | ((a2 & 255) << 16) | (a3 << 24);
    }
    o[i] = make_int4(q[0], q[1], q[2], q[3]);
  }
}

// ======== 256x256 i8 GEMM, ONE barrier per K-tile ========
// C[t][o] = (x_q[t][:] . w_q[o][:]) * scale[t].  i32 accumulate (exact).
// 8 waves (2Mx4N), per-wave 128x64 out, BKB=128 B, 128 KiB LDS dbuf.
// Per tile t:
//   R1: all 24 ds_read_b128 (aF,bF,aS) + 32 MFMA (m0-3 x n0-3)
//   mid: s_waitcnt vmcnt(0) lgkmcnt(0); s_barrier
//        -> (a) every wave's reads of buf[t] retired  => buf[t] dead
//        -> (b) every wave's staging of buf[t+1] done => buf[t+1] resident
//   R2: stage tile t+2 into buf[t&1] (just freed) + 32 pure-reg MFMA (m4-7)
//   (no trailing barrier: next R1 reads buf[t+1], resident since mid; the
//    compiler may pipeline R1(t+1) ds_reads under R2(t) MFMAs across the
//    backedge, and waves free-run between barriers.)
// mid(t+1)'s vmcnt(0) drains stage(t+2) with ~1.25-tile lead >> HBM latency.
__global__ __launch_bounds__(512, 2) void bin_gemm_i8(const char* __restrict__ A,
                                                      const char* __restrict__ B,
                                                      const float* __restrict__ scales,
                                                      float* __restrict__ C) {
  __shared__ char lds[131072];   // 2 buf x (A 32KB + B 32KB)

  const int tid  = threadIdx.x;
  const int w    = tid >> 6;
  const int lane = tid & 63;
  const int lr   = lane & 15;    // fragment row/col
  const int lk   = lane >> 4;    // k-group 0..3 (16 bytes each)
  const int wr   = w >> 2;       // wave row 0..1  (128 rows each)
  const int wc   = w & 3;        // wave col 0..3  (64 cols each)

  const int bm = blockIdx.x >> 4;     // M/256 = 32
  const int bn = blockIdx.x & 15;     // N/256 = 16

  const char* Ag = A + (size_t)bm * BM * K_IN;
  const char* Bg = B + (size_t)bn * BN * K_IN;

  // staging: linear LDS dest + inverse-swizzled global source (rule #21).
  // chunk c (16B) of a 128-row half: row r=c>>3, source slot (c^r)&7.
  const int c0 = w * 128 + lane;
  const int c1 = c0 + 64;
  const int r0 = c0 >> 3, r1 = c1 >> 3;
  const size_t g0 = (size_t)r0 * K_IN + (size_t)(((c0 ^ r0) & 7) << 4);
  const size_t g1 = (size_t)r1 * K_IN + (size_t)(((c1 ^ r1) & 7) << 4);
  const int ldsw = w * 128 * 16;

  auto stage = [&](int mat, int half, int tt) {
    const char* g = (mat ? Bg : Ag) + (size_t)half * (128 * K_IN)
                                    + (size_t)tt * BKB;
    char* l = &lds[((tt & 1) << 16) + (mat << 15) + (half << 14) + ldsw];
    GLOAD_LDS16(g + g0, l);
    GLOAD_LDS16(g + g1, l + 1024);
  };

  // fragment reads (swizzled): (row)*128 + ((ks*64 + lk*16) ^ ((row&7)<<4));
  // row&7 == lr&7 for all fragments (16-row strides).
  const int swz   = (lr & 7) << 4;
  const int a_row = (wr * 128 + lr) * 128;
  const int b_row = 32768 + (wc * 64 + lr) * 128;
  const int k0 = (lk * 16) ^ swz;          // k bytes 0..63
  const int k1 = (64 + lk * 16) ^ swz;     // k bytes 64..127

  i32x4 acc[8][4];
  #pragma unroll
  for (int m = 0; m < 8; ++m)
    #pragma unroll
    for (int n = 0; n < 4; ++n) { i32x4 z = {0, 0, 0, 0}; acc[m][n] = z; }

  // prologue: tile 0 (8 loads) then tile 1 (8 loads); wait tile 0 complete.
  stage(0, 0, 0); stage(0, 1, 0); stage(1, 0, 0); stage(1, 1, 0);
  stage(0, 0, 1); stage(0, 1, 1); stage(1, 0, 1); stage(1, 1, 1);
  VMCNT8();
  BAR();

  for (int t = 0; t < NT; ++t) {
    const char* L = &lds[(size_t)(t & 1) << 16];
    i32x4 aF[4][2], aS[4][2], bF[4][2];

    // ================= R1: all 24 reads + MFMA m0-3 x n0-3 ================
    #pragma unroll
    for (int m = 0; m < 4; ++m) {
      aF[m][0] = *(const i32x4*)(L + a_row + m * 2048 + k0);
      aF[m][1] = *(const i32x4*)(L + a_row + m * 2048 + k1);
    }
    #pragma unroll
    for (int n = 0; n < 4; ++n) {
      bF[n][0] = *(const i32x4*)(L + b_row + n * 2048 + k0);
      bF[n][1] = *(const i32x4*)(L + b_row + n * 2048 + k1);
    }
    #pragma unroll
    for (int m = 0; m < 4; ++m) {
      aS[m][0] = *(const i32x4*)(L + a_row + 8192 + m * 2048 + k0);
      aS[m][1] = *(const i32x4*)(L + a_row + 8192 + m * 2048 + k1);
    }
    #pragma unroll
    for (int m = 0; m < 4; ++m)
      #pragma unroll
      for (int n = 0; n < 4; ++n) {
        acc[m][n] = MFMAI8(aF[m][0], bF[n][0], acc[m][n]);
        acc[m][n] = MFMAI8(aF[m][1], bF[n][1], acc[m][n]);
      }

    // ---- mid: single sync point (see header comment)
    WAITALL();
    BAR();

    // ================= R2: stage t+2 + MFMA m4-7 x n0-3 ===================
    if (t + 2 < NT) {
      stage(1, 0, t + 2); stage(1, 1, t + 2);   // B halves
      stage(0, 0, t + 2); stage(0, 1, t + 2);   // A halves
    }
    PRIO(1);
    #pragma unroll
    for (int m = 0; m < 4; ++m)
      #pragma unroll
      for (int n = 0; n < 4; ++n) {
        acc[4 + m][n] = MFMAI8(aS[m][0], bF[n][0], acc[4 + m][n]);
        acc[4 + m][n] = MFMAI8(aS[m][1], bF[n][1], acc[4 + m][n]);
      }
    PRIO(0);
  }

  // epilogue: C/D layout col=lane&15, row=(lane>>4)*4+reg; y = acc * scale[row]
  const int grow0 = bm * BM + wr * 128;
  float scl[8][4];
  #pragma unroll
  for (int m = 0; m < 8; ++m)
    #pragma unroll
    for (int j = 0; j < 4; ++j)
      scl[m][j] = scales[grow0 + m * 16 + lk * 4 + j];

  float* Cp = C + (size_t)grow0 * N_OUT + bn * BN + wc * 64;
  #pragma unroll
  for (int m = 0; m < 8; ++m)
    #pragma unroll
    for (int n = 0; n < 4; ++n)
      #pragma unroll
      for (int j = 0; j < 4; ++j)
        Cp[(size_t)(m * 16 + lk * 4 + j) * N_OUT + n * 16 + lr] =
            (float)acc[m][n][j] * scl[m][j];
}

// ---------------- fallback (ws too small): fp32 LDS-tiled, correct but slow --
__global__ __launch_bounds__(256) void fb_gemm(const float* __restrict__ x,
                                               const float* __restrict__ W,
                                               float* __restrict__ y) {
  __shared__ float xs[32][33];
  __shared__ float ws[32][33];
  const int bx = blockIdx.x;
  const int by = blockIdx.y;
  const int tx = threadIdx.x & 31;
  const int ty = threadIdx.x >> 5;
  float acc[4] = {0.f, 0.f, 0.f, 0.f};
  for (int k0 = 0; k0 < K_IN; k0 += 32) {
    #pragma unroll
    for (int i = 0; i < 4; ++i) {
      int r = ty + i * 8;
      xs[r][tx] = x[(size_t)(by * 32 + r) * K_IN + k0 + tx];
      float wv = W[(size_t)(bx * 32 + r) * K_IN + k0 + tx];
      ws[r][tx] = wv > 0.f ? 1.f : (wv < 0.f ? -1.f : 0.f);
    }
    __syncthreads();
    #pragma unroll
    for (int i = 0; i < 4; ++i) {
      int r = ty + i * 8;
      float s = acc[i];
      #pragma unroll
      for (int k = 0; k < 32; ++k) s += xs[r][k] * ws[tx][k];
      acc[i] = s;
    }
    __syncthreads();
  }
  #pragma unroll
  for (int i = 0; i < 4; ++i)
    y[(size_t)(by * 32 + ty + i * 8) * N_OUT + bx * 32 + tx] = acc[i];
}

extern "C" void kernel_launch(void* const* d_in, const int* in_sizes, int n_in,
                              void* d_out, int out_size, void* d_ws, size_t ws_size,
                              hipStream_t stream) {
  const float* x = (const float*)d_in[0];   // [8192, 4096]
  const float* W = (const float*)d_in[1];   // [4096, 4096]
  float* y = (float*)d_out;                 // [8192, 4096]

  const size_t need = (size_t)M_TOK * K_IN + (size_t)N_OUT * K_IN
                    + (size_t)M_TOK * sizeof(float);
  if (ws_size >= need) {
    char*  xq = (char*)d_ws;
    char*  wq = xq + (size_t)M_TOK * K_IN;
    float* sc = (float*)(wq + (size_t)N_OUT * K_IN);
    quant_x_i8<<<M_TOK, 256, 0, stream>>>((const float4*)x, (int4*)xq, sc);
    sgn_w_i8<<<2048, 256, 0, stream>>>((const float4*)W, (int4*)wq,
                                       N_OUT * K_IN / 16);
    bin_gemm_i8<<<(M_TOK / BM) * (N_OUT / BN), 512, 0, stream>>>(xq, wq, sc, y);
  } else {
    dim3 g(N_OUT / 32, M_TOK / 32);
    fb_gemm<<<g, 256, 0, stream>>>(x, W, y);
  }
}